// Round 7
// baseline (293.925 us; speedup 1.0000x reference)
//
#include <hip/hip_runtime.h>
#include <hip/hip_bf16.h>
#include <cstdint>
#include <cstddef>

// B=4, S=2048, D=1024, H=16, DH=64, M = B*S = 8192
#define S_ 2048
#define D_ 1024
#define H_ 16
#define DH_ 64
#define M_ 8192

using bf16 = __bf16;
using bf16x4 = __attribute__((ext_vector_type(4))) __bf16;
using bf16x8 = __attribute__((ext_vector_type(8))) __bf16;
using f32x4 = __attribute__((ext_vector_type(4))) float;
using s16x4 = __attribute__((ext_vector_type(4))) short;

__device__ __forceinline__ void g2lds16(const bf16* g, bf16* l) {
  __builtin_amdgcn_global_load_lds(
      (const __attribute__((address_space(1))) void*)g,
      (__attribute__((address_space(3))) void*)l, 16, 0, 0);
}

// 16x16x16 bf16 MFMA (A: 4 bf16/lane, k=quad*4+i; C/D: standard 4-reg layout)
__device__ __forceinline__ f32x4 mfma16(bf16x4 a, bf16x4 b, f32x4 c) {
#if __has_builtin(__builtin_amdgcn_mfma_f32_16x16x16_bf16)
  return __builtin_amdgcn_mfma_f32_16x16x16_bf16(a, b, c, 0, 0, 0);
#elif __has_builtin(__builtin_amdgcn_mfma_f32_16x16x16bf16_1k)
  return __builtin_amdgcn_mfma_f32_16x16x16bf16_1k(
      __builtin_bit_cast(s16x4, a), __builtin_bit_cast(s16x4, b), c, 0, 0, 0);
#else
  f32x4 d;
  asm("v_mfma_f32_16x16x16_bf16 %0, %1, %2, %3"
      : "=v"(d)
      : "v"(a), "v"(b), "v"(c));
  return d;
#endif
}

// ------- fused fp32->bf16 converts: x (blocks 0..4095) + 4 weights^T -------
__global__ __launch_bounds__(256) void cvt_all_kernel(
    const float* __restrict__ x, const float* __restrict__ w0,
    const float* __restrict__ w1, const float* __restrict__ w2,
    const float* __restrict__ w3, bf16* __restrict__ xb,
    bf16* __restrict__ o0, bf16* __restrict__ o1, bf16* __restrict__ o2,
    bf16* __restrict__ o3) {
  __shared__ float tile[32][33];
  int bx = blockIdx.x;
  int tid = threadIdx.x;
  if (bx < 4096) {
    size_t i = ((size_t)bx * 256 + tid) * 8;
    float4 a = *(const float4*)(x + i);
    float4 b = *(const float4*)(x + i + 4);
    bf16x8 o;
    o[0] = (bf16)a.x; o[1] = (bf16)a.y; o[2] = (bf16)a.z; o[3] = (bf16)a.w;
    o[4] = (bf16)b.x; o[5] = (bf16)b.y; o[6] = (bf16)b.z; o[7] = (bf16)b.w;
    *(bf16x8*)(xb + i) = o;
    return;
  }
  int wb = bx - 4096;
  int wsel = wb >> 10; wb &= 1023;
  const float* W; bf16* O;
  switch (wsel) {
    case 0: W = w0; O = o0; break;
    case 1: W = w1; O = o1; break;
    case 2: W = w2; O = o2; break;
    default: W = w3; O = o3; break;
  }
  int n0 = (wb & 31) * 32;
  int k0 = (wb >> 5) * 32;
#pragma unroll
  for (int i = 0; i < 4; ++i) {
    int e = tid + i * 256; int rr = e >> 5, cc = e & 31;
    tile[rr][cc] = W[(size_t)(k0 + rr) * 1024 + n0 + cc];
  }
  __syncthreads();
#pragma unroll
  for (int i = 0; i < 4; ++i) {
    int e = tid + i * 256; int rr = e >> 5, cc = e & 31;
    O[(size_t)(n0 + rr) * 1024 + k0 + cc] = (bf16)tile[cc][rr];
  }
}

// ------- GEMM v2: C = A @ Bt^T, double-buffered LDS + vmcnt(4) raw-barrier
// pipeline (prefetch stays in flight across barrier) + XOR-swizzled LDS
// (2-way max bank aliasing on frag reads).
// which==2 (V) blocks swap MFMA operands to produce C^T directly.
template <int MODE>
__global__ __launch_bounds__(256) void gemm_kernel(
    const bf16* __restrict__ A,
    const bf16* __restrict__ Bt0, const bf16* __restrict__ Bt1,
    const bf16* __restrict__ Bt2,
    bf16* __restrict__ Qo, bf16* __restrict__ Ko, bf16* __restrict__ Vto,
    const float* __restrict__ xres, float* __restrict__ out) {
  __shared__ __align__(16) bf16 smA[2][128 * 32];
  __shared__ __align__(16) bf16 smB[2][128 * 32];
  constexpr int NBLK = (MODE == 0) ? 24 : 8;
  int bm = blockIdx.x / NBLK, bn = blockIdx.x % NBLK;
  int m0 = bm * 128;
  const bf16* Bt; int which = 0, n0;
  if constexpr (MODE == 0) {
    which = bn >> 3; n0 = (bn & 7) * 128;
    Bt = (which == 0) ? Bt0 : (which == 1 ? Bt1 : Bt2);
  } else { n0 = bn * 128; Bt = Bt0; }

  int tid = threadIdx.x;
  int wave = tid >> 6, lane = tid & 63;
  int quad = lane >> 4, r = lane & 15;
  int wm = (wave >> 1) * 64, wn = (wave & 1) * 64;

  f32x4 acc[4][4];
  f32x4 zero = {0.f, 0.f, 0.f, 0.f};
#pragma unroll
  for (int i = 0; i < 4; ++i)
#pragma unroll
    for (int j = 0; j < 4; ++j) acc[i][j] = zero;

  int c0 = 2 * wave, c1 = 2 * wave + 1;
  int rA0 = c0 * 16 + (lane >> 2);
  int rA1 = c1 * 16 + (lane >> 2);
  // XOR-swizzled staging k-chunk: lane loads global chunk (lane&3)^((lane>>3)&3)
  int kc = (((lane & 3) ^ ((lane >> 3) & 3)) * 8);
  // reader chunk offsets (inverse swizzle)
  const int rx = ((r >> 1) & 3);

  auto stage = [&](int k0, bf16* bufA, bf16* bufB) {
    const bf16 *gA0, *gA1;
    if constexpr (MODE == 0) {
      gA0 = A + (size_t)(m0 + rA0) * 1024 + k0 + kc;
      gA1 = A + (size_t)(m0 + rA1) * 1024 + k0 + kc;
    } else {
      int kk0 = k0 + kc, h = kk0 >> 6, dh = kk0 & 63;
      int mm0 = m0 + rA0, mm1 = m0 + rA1;
      gA0 = A + ((size_t)((mm0 >> 11) * H_ + h) * S_ + (mm0 & 2047)) * DH_ + dh;
      gA1 = A + ((size_t)((mm1 >> 11) * H_ + h) * S_ + (mm1 & 2047)) * DH_ + dh;
    }
    g2lds16(gA0, bufA + c0 * 512);
    g2lds16(gA1, bufA + c1 * 512);
    g2lds16(Bt + (size_t)(n0 + rA0) * 1024 + k0 + kc, bufB + c0 * 512);
    g2lds16(Bt + (size_t)(n0 + rA1) * 1024 + k0 + kc, bufB + c1 * 512);
  };

  stage(0, &smA[0][0], &smB[0][0]);

  for (int kt = 0; kt < 32; ++kt) {
    const int cur = kt & 1;
    if (kt + 1 < 32) {
      stage((kt + 1) * 32, &smA[1 - cur][0], &smB[1 - cur][0]);
      asm volatile("s_waitcnt vmcnt(4)\n\ts_barrier" ::: "memory");
    } else {
      asm volatile("s_waitcnt vmcnt(0)\n\ts_barrier" ::: "memory");
    }
    bf16x8 af[4], bfr[4];
#pragma unroll
    for (int i = 0; i < 4; ++i)
      af[i] = *(const bf16x8*)(&smA[cur][0] + (wm + i * 16 + r) * 32 +
                               (quad ^ rx) * 8);
#pragma unroll
    for (int j = 0; j < 4; ++j)
      bfr[j] = *(const bf16x8*)(&smB[cur][0] + (wn + j * 16 + r) * 32 +
                                (quad ^ rx) * 8);
    if (which == 2) {  // C^T for coalesced Vt stores
#pragma unroll
      for (int i = 0; i < 4; ++i)
#pragma unroll
        for (int j = 0; j < 4; ++j)
          acc[i][j] = __builtin_amdgcn_mfma_f32_16x16x32_bf16(bfr[i], af[j],
                                                              acc[i][j], 0, 0, 0);
    } else {
#pragma unroll
      for (int i = 0; i < 4; ++i)
#pragma unroll
        for (int j = 0; j < 4; ++j)
          acc[i][j] = __builtin_amdgcn_mfma_f32_16x16x32_bf16(af[i], bfr[j],
                                                              acc[i][j], 0, 0, 0);
    }
    // all waves done reading buf[cur] before next iter's prefetch overwrites it
    asm volatile("s_waitcnt lgkmcnt(0)\n\ts_barrier" ::: "memory");
  }

  if (which == 2) {  // acc[i][j]: row=n (dh), col=m (s)
#pragma unroll
    for (int i = 0; i < 4; ++i) {
#pragma unroll
      for (int j = 0; j < 4; ++j) {
#pragma unroll
        for (int g = 0; g < 4; ++g) {
          int n = n0 + wn + i * 16 + quad * 4 + g;
          int m = m0 + wm + j * 16 + r;
          Vto[((size_t)((m >> 11) * H_ + (n >> 6)) * DH_ + (n & 63)) * S_ +
              (m & 2047)] = (bf16)acc[i][j][g];
        }
      }
    }
    return;
  }
#pragma unroll
  for (int i = 0; i < 4; ++i) {
#pragma unroll
    for (int j = 0; j < 4; ++j) {
#pragma unroll
      for (int g = 0; g < 4; ++g) {
        int m = m0 + wm + i * 16 + quad * 4 + g;
        int n = n0 + wn + j * 16 + r;
        float v = acc[i][j][g];
        if constexpr (MODE == 0) {
          int b = m >> 11, s = m & 2047, h = n >> 6, dh = n & 63;
          if (which == 0)
            Qo[((size_t)(b * H_ + h) * S_ + s) * DH_ + dh] = (bf16)v;
          else
            Ko[((size_t)(b * H_ + h) * S_ + s) * DH_ + dh] = (bf16)v;
        } else {
          size_t idx = (size_t)m * 1024 + n;
          out[idx] = v + xres[idx];
        }
      }
    }
  }
}

// ------ flash attention v5: 32q/wave, register P (no LDS transpose) ------
// grid = 512: bh = bx & 63 (XCD-local), p = bx >> 6 pairs 128-q tiles
// (p, 15-p): 34 kv-64 iters each. S^T C-layout == A-operand layout of
// 16x16x16 MFMA -> PV directly from registers. Static-max softmax.
__global__ __launch_bounds__(256) void attn_kernel(const bf16* __restrict__ Qb,
                                                   const bf16* __restrict__ Kb,
                                                   const bf16* __restrict__ Vtb,
                                                   bf16* __restrict__ ctx) {
  __shared__ __align__(16) bf16 smK[2][64 * 64];
  __shared__ __align__(16) bf16 smV[2][64 * 64];
  const int bh = blockIdx.x & 63, p = blockIdx.x >> 6;
  const bf16* Qh = Qb + (size_t)bh * S_ * DH_;
  const bf16* Kh = Kb + (size_t)bh * S_ * DH_;
  const bf16* Vh = Vtb + (size_t)bh * DH_ * S_;
  bf16* Ch = ctx + (size_t)bh * S_ * DH_;
  const int tid = threadIdx.x, wave = tid >> 6, lane = tid & 63;
  const int quad = lane >> 4, r = lane & 15;
  const int r7 = r & 7;
  const int c0 = 2 * wave, c1 = c0 + 1;
  const int sr = lane >> 3;
  const int gcol = ((lane & 7) ^ (sr & 7)) * 8;  // source-side XOR swizzle
  const f32x4 zero = {0.f, 0.f, 0.f, 0.f};
  const int xk0 = (quad ^ r7) * 8, xk1 = ((quad + 4) ^ r7) * 8;

  for (int ph = 0; ph < 2; ++ph) {
    const int i128 = ph ? (15 - p) : p;
    const int qB = i128 * 128;
    const int q0w = qB + wave * 32;
    const int numkt = 2 * i128 + 2;

    bf16x8 qf[2][2];
    const float qsc = 0.125f * 1.44269504f;  // 1/sqrt(64) * log2(e)
#pragma unroll
    for (int qg = 0; qg < 2; ++qg)
#pragma unroll
      for (int hh = 0; hh < 2; ++hh) {
        bf16x8 q = *(const bf16x8*)(Qh + (size_t)(q0w + qg * 16 + r) * DH_ +
                                    hh * 32 + quad * 8);
#pragma unroll
        for (int i = 0; i < 8; ++i) q[i] = (bf16)((float)q[i] * qsc);
        qf[qg][hh] = q;
      }

    f32x4 lacc[2] = {zero, zero};
    f32x4 oacc[2][4];
#pragma unroll
    for (int qg = 0; qg < 2; ++qg)
#pragma unroll
      for (int tn = 0; tn < 4; ++tn) oacc[qg][tn] = zero;

    // prologue: tile 0 -> buffer 0
    g2lds16(Kh + (size_t)(c0 * 8 + sr) * DH_ + gcol, &smK[0][c0 * 512]);
    g2lds16(Kh + (size_t)(c1 * 8 + sr) * DH_ + gcol, &smK[0][c1 * 512]);
    g2lds16(Vh + (size_t)(c0 * 8 + sr) * S_ + gcol, &smV[0][c0 * 512]);
    g2lds16(Vh + (size_t)(c1 * 8 + sr) * S_ + gcol, &smV[0][c1 * 512]);

    for (int kt = 0; kt < numkt; ++kt) {
      const int cur = kt & 1;
      const int kv0 = kt * 64;
      if (kt + 1 < numkt) {  // prefetch next tile into other buffer
        const int nk = kv0 + 64;
        g2lds16(Kh + (size_t)(nk + c0 * 8 + sr) * DH_ + gcol, &smK[1 - cur][c0 * 512]);
        g2lds16(Kh + (size_t)(nk + c1 * 8 + sr) * DH_ + gcol, &smK[1 - cur][c1 * 512]);
        g2lds16(Vh + (size_t)(c0 * 8 + sr) * S_ + nk + gcol, &smV[1 - cur][c0 * 512]);
        g2lds16(Vh + (size_t)(c1 * 8 + sr) * S_ + nk + gcol, &smV[1 - cur][c1 * 512]);
        asm volatile("s_waitcnt vmcnt(4)\n\ts_barrier" ::: "memory");
      } else {
        asm volatile("s_waitcnt vmcnt(0)\n\ts_barrier" ::: "memory");
      }
      if (kv0 <= q0w + 31) {  // wave not fully masked for this kv tile
        const bf16* kb = &smK[cur][0];
        const bf16* vb = &smV[cur][0];

        // S^T: s[qg][t][g] = S[kv=kv0+t*16+quad*4+g][q=q0w+qg*16+r]
        f32x4 s[2][4];
#pragma unroll
        for (int t = 0; t < 4; ++t) {
          bf16x8 kf0 = *(const bf16x8*)(kb + (t * 16 + r) * 64 + xk0);
          bf16x8 kf1 = *(const bf16x8*)(kb + (t * 16 + r) * 64 + xk1);
#pragma unroll
          for (int qg = 0; qg < 2; ++qg) {
            f32x4 z = __builtin_amdgcn_mfma_f32_16x16x32_bf16(kf0, qf[qg][0],
                                                              zero, 0, 0, 0);
            s[qg][t] = __builtin_amdgcn_mfma_f32_16x16x32_bf16(kf1, qf[qg][1],
                                                               z, 0, 0, 0);
          }
        }
        if (kt >= numkt - 2) {  // diagonal region: causal mask
#pragma unroll
          for (int qg = 0; qg < 2; ++qg) {
            const int q = q0w + qg * 16 + r;
#pragma unroll
            for (int t = 0; t < 4; ++t) {
              const int kv = kv0 + t * 16 + quad * 4;
#pragma unroll
              for (int g = 0; g < 4; ++g)
                if (kv + g > q) s[qg][t][g] = -1e30f;
            }
          }
        }
        // P = exp2(s); l accumulate; PV via 16x16x16 MFMA (P from registers)
#pragma unroll
        for (int t = 0; t < 4; ++t) {
          bf16x4 pa[2];
#pragma unroll
          for (int qg = 0; qg < 2; ++qg) {
#pragma unroll
            for (int g = 0; g < 4; ++g)
              s[qg][t][g] = __builtin_amdgcn_exp2f(s[qg][t][g]);
            lacc[qg] += s[qg][t];
            bf16x4 pk;
#pragma unroll
            for (int g = 0; g < 4; ++g) pk[g] = (bf16)s[qg][t][g];
            pa[qg] = pk;
          }
#pragma unroll
          for (int tn = 0; tn < 4; ++tn) {
            bf16x4 vf = *(const bf16x4*)(
                vb + (tn * 16 + r) * 64 +
                ((2 * t + (quad >> 1)) ^ r7) * 8 + (quad & 1) * 4);
            oacc[0][tn] = mfma16(pa[0], vf, oacc[0][tn]);
            oacc[1][tn] = mfma16(pa[1], vf, oacc[1][tn]);
          }
        }
      }
      // all waves done reading cur buffers before next iter overwrites them
      asm volatile("s_waitcnt lgkmcnt(0)\n\ts_barrier" ::: "memory");
    }

    // epilogue: reduce l per q (= lane r) per qg, normalize, store
#pragma unroll
    for (int qg = 0; qg < 2; ++qg) {
      float rs = (lacc[qg][0] + lacc[qg][1]) + (lacc[qg][2] + lacc[qg][3]);
      rs += __shfl_xor(rs, 16, 64);
      rs += __shfl_xor(rs, 32, 64);
      const float inv = 1.f / rs;
      f32x4 ib;
#pragma unroll
      for (int g = 0; g < 4; ++g) ib[g] = __shfl(inv, quad * 4 + g, 64);
#pragma unroll
      for (int tn = 0; tn < 4; ++tn) {
        f32x4 ov = oacc[qg][tn] * ib;
#pragma unroll
        for (int g = 0; g < 4; ++g)
          Ch[(size_t)(q0w + qg * 16 + quad * 4 + g) * DH_ + tn * 16 + r] =
              (bf16)ov[g];
      }
    }
  }
}

// ---------------- LayerNorm in-place on d_out ----------------
__global__ __launch_bounds__(256) void ln_kernel(float* __restrict__ out,
                                                 const float* __restrict__ gamma,
                                                 const float* __restrict__ beta) {
  __shared__ float red[8];
  size_t row = blockIdx.x;
  float* p = out + row * 1024;
  int tid = threadIdx.x;
  float4 v = ((const float4*)p)[tid];
  float s1 = v.x + v.y + v.z + v.w;
  float s2 = v.x * v.x + v.y * v.y + v.z * v.z + v.w * v.w;
#pragma unroll
  for (int o = 1; o < 64; o <<= 1) {
    s1 += __shfl_xor(s1, o, 64);
    s2 += __shfl_xor(s2, o, 64);
  }
  int wave = tid >> 6, lane = tid & 63;
  if (lane == 0) { red[wave] = s1; red[4 + wave] = s2; }
  __syncthreads();
  s1 = red[0] + red[1] + red[2] + red[3];
  s2 = red[4] + red[5] + red[6] + red[7];
  float mean = s1 * (1.f / 1024.f);
  float var = s2 * (1.f / 1024.f) - mean * mean;
  float rstd = rsqrtf(var + 1e-5f);
  float4 g = ((const float4*)gamma)[tid];
  float4 b = ((const float4*)beta)[tid];
  float4 o;
  o.x = (v.x - mean) * rstd * g.x + b.x;
  o.y = (v.y - mean) * rstd * g.y + b.y;
  o.z = (v.z - mean) * rstd * g.z + b.z;
  o.w = (v.w - mean) * rstd * g.w + b.w;
  ((float4*)p)[tid] = o;
}

extern "C" void kernel_launch(void* const* d_in, const int* in_sizes, int n_in,
                              void* d_out, int out_size, void* d_ws,
                              size_t ws_size, hipStream_t stream) {
  (void)in_sizes; (void)n_in; (void)out_size; (void)ws_size;
  const float* x  = (const float*)d_in[0];
  const float* WQ = (const float*)d_in[1];
  const float* WK = (const float*)d_in[2];
  const float* WV = (const float*)d_in[3];
  const float* WO = (const float*)d_in[4];
  const float* gamma = (const float*)d_in[5];
  const float* beta  = (const float*)d_in[6];
  float* out = (float*)d_out;

  bf16* ws = (bf16*)d_ws;
  const size_t MD = (size_t)M_ * D_;
  const size_t WW = (size_t)D_ * D_;
  bf16* xb   = ws;
  bf16* wqt  = xb + MD;
  bf16* wkt  = wqt + WW;
  bf16* wvt  = wkt + WW;
  bf16* wot  = wvt + WW;
  bf16* Qb   = wot + WW;
  bf16* Kb   = Qb + MD;
  bf16* Vtb  = Kb + MD;
  bf16* ctxb = Vtb + MD;

  cvt_all_kernel<<<dim3(8192), dim3(256), 0, stream>>>(
      x, WQ, WK, WV, WO, xb, wqt, wkt, wvt, wot);
  gemm_kernel<0><<<dim3(64 * 24), dim3(256), 0, stream>>>(
      xb, wqt, wkt, wvt, Qb, Kb, Vtb, nullptr, nullptr);
  attn_kernel<<<dim3(512), dim3(256), 0, stream>>>(Qb, Kb, Vtb, ctxb);
  gemm_kernel<1><<<dim3(64 * 8), dim3(256), 0, stream>>>(
      ctxb, wot, nullptr, nullptr, nullptr, nullptr, nullptr, x, out);
  ln_kernel<<<dim3(8192), dim3(256), 0, stream>>>(out, gamma, beta);
}

// Round 8
// 269.092 us; speedup vs baseline: 1.0923x; 1.0923x over previous
//
#include <hip/hip_runtime.h>
#include <hip/hip_bf16.h>
#include <cstdint>
#include <cstddef>

// B=4, S=2048, D=1024, H=16, DH=64, M = B*S = 8192
#define S_ 2048
#define D_ 1024
#define H_ 16
#define DH_ 64
#define M_ 8192

using bf16 = __bf16;
using bf16x4 = __attribute__((ext_vector_type(4))) __bf16;
using bf16x8 = __attribute__((ext_vector_type(8))) __bf16;
using f32x4 = __attribute__((ext_vector_type(4))) float;
using s16x4 = __attribute__((ext_vector_type(4))) short;

__device__ __forceinline__ void g2lds16(const bf16* g, bf16* l) {
  __builtin_amdgcn_global_load_lds(
      (const __attribute__((address_space(1))) void*)g,
      (__attribute__((address_space(3))) void*)l, 16, 0, 0);
}

// 16x16x16 bf16 MFMA (A: 4 bf16/lane, k=quad*4+i; C/D: standard 4-reg layout)
__device__ __forceinline__ f32x4 mfma16(bf16x4 a, bf16x4 b, f32x4 c) {
#if __has_builtin(__builtin_amdgcn_mfma_f32_16x16x16_bf16)
  return __builtin_amdgcn_mfma_f32_16x16x16_bf16(a, b, c, 0, 0, 0);
#elif __has_builtin(__builtin_amdgcn_mfma_f32_16x16x16bf16_1k)
  return __builtin_amdgcn_mfma_f32_16x16x16bf16_1k(
      __builtin_bit_cast(s16x4, a), __builtin_bit_cast(s16x4, b), c, 0, 0, 0);
#else
  f32x4 d;
  asm("v_mfma_f32_16x16x16_bf16 %0, %1, %2, %3"
      : "=v"(d)
      : "v"(a), "v"(b), "v"(c));
  return d;
#endif
}

// ------- fused fp32->bf16 converts: x (blocks 0..4095) + 4 weights^T -------
__global__ __launch_bounds__(256) void cvt_all_kernel(
    const float* __restrict__ x, const float* __restrict__ w0,
    const float* __restrict__ w1, const float* __restrict__ w2,
    const float* __restrict__ w3, bf16* __restrict__ xb,
    bf16* __restrict__ o0, bf16* __restrict__ o1, bf16* __restrict__ o2,
    bf16* __restrict__ o3) {
  __shared__ float tile[32][33];
  int bx = blockIdx.x;
  int tid = threadIdx.x;
  if (bx < 4096) {
    size_t i = ((size_t)bx * 256 + tid) * 8;
    float4 a = *(const float4*)(x + i);
    float4 b = *(const float4*)(x + i + 4);
    bf16x8 o;
    o[0] = (bf16)a.x; o[1] = (bf16)a.y; o[2] = (bf16)a.z; o[3] = (bf16)a.w;
    o[4] = (bf16)b.x; o[5] = (bf16)b.y; o[6] = (bf16)b.z; o[7] = (bf16)b.w;
    *(bf16x8*)(xb + i) = o;
    return;
  }
  int wb = bx - 4096;
  int wsel = wb >> 10; wb &= 1023;
  const float* W; bf16* O;
  switch (wsel) {
    case 0: W = w0; O = o0; break;
    case 1: W = w1; O = o1; break;
    case 2: W = w2; O = o2; break;
    default: W = w3; O = o3; break;
  }
  int n0 = (wb & 31) * 32;
  int k0 = (wb >> 5) * 32;
#pragma unroll
  for (int i = 0; i < 4; ++i) {
    int e = tid + i * 256; int rr = e >> 5, cc = e & 31;
    tile[rr][cc] = W[(size_t)(k0 + rr) * 1024 + n0 + cc];
  }
  __syncthreads();
#pragma unroll
  for (int i = 0; i < 4; ++i) {
    int e = tid + i * 256; int rr = e >> 5, cc = e & 31;
    O[(size_t)(n0 + rr) * 1024 + k0 + cc] = (bf16)tile[cc][rr];
  }
}

// ------- GEMM v3: dbuf + vmcnt(4) pipeline + XOR swizzle, with hand
// strength-reduced staging pointers (constant increments) and K-loop
// unrolled x2 so the buffer index is compile-time (no runtime selects).
// which==2 (V) swaps MFMA operands to emit C^T (coalesced Vt stores).
template <int MODE>
__global__ __launch_bounds__(256) void gemm_kernel(
    const bf16* __restrict__ A,
    const bf16* __restrict__ Bt0, const bf16* __restrict__ Bt1,
    const bf16* __restrict__ Bt2,
    bf16* __restrict__ Qo, bf16* __restrict__ Ko, bf16* __restrict__ Vto,
    const float* __restrict__ xres, float* __restrict__ out) {
  __shared__ __align__(16) bf16 smA0[128 * 32], smA1[128 * 32];
  __shared__ __align__(16) bf16 smB0[128 * 32], smB1[128 * 32];
  constexpr int NBLK = (MODE == 0) ? 24 : 8;
  int bm = blockIdx.x / NBLK, bn = blockIdx.x % NBLK;
  int m0 = bm * 128;
  const bf16* Bt; int which = 0, n0;
  if constexpr (MODE == 0) {
    which = bn >> 3; n0 = (bn & 7) * 128;
    Bt = (which == 0) ? Bt0 : (which == 1 ? Bt1 : Bt2);
  } else { n0 = bn * 128; Bt = Bt0; }

  int tid = threadIdx.x;
  int wave = tid >> 6, lane = tid & 63;
  int quad = lane >> 4, r = lane & 15;
  int wm = (wave >> 1) * 64, wn = (wave & 1) * 64;

  f32x4 acc[4][4];
  f32x4 zero = {0.f, 0.f, 0.f, 0.f};
#pragma unroll
  for (int i = 0; i < 4; ++i)
#pragma unroll
    for (int j = 0; j < 4; ++j) acc[i][j] = zero;

  int c0 = 2 * wave, c1 = 2 * wave + 1;
  int rA0 = c0 * 16 + (lane >> 2);
  int rA1 = c1 * 16 + (lane >> 2);
  // XOR-swizzled staging k-chunk: lane loads global chunk (lane&3)^((lane>>3)&3)
  int kc = ((lane & 3) ^ ((lane >> 3) & 3)) * 8;
  const int rx = (r >> 1) & 3;  // reader inverse-swizzle

  // hoisted, incrementally-advanced staging pointers
  const bf16 *pA0, *pA1;
  if constexpr (MODE == 0) {
    pA0 = A + (size_t)(m0 + rA0) * 1024 + kc;
    pA1 = A + (size_t)(m0 + rA1) * 1024 + kc;
  } else {
    // A is ctx [B,H,S,DH]; k = h*64+dh. kc<32 so even k-tiles have dh=kc.
    int mm0 = m0 + rA0, mm1 = m0 + rA1;
    pA0 = A + ((size_t)((mm0 >> 11) * H_) * S_ + (mm0 & 2047)) * DH_ + kc;
    pA1 = A + ((size_t)((mm1 >> 11) * H_) * S_ + (mm1 & 2047)) * DH_ + kc;
  }
  const bf16* pB0 = Bt + (size_t)(n0 + rA0) * 1024 + kc;
  const bf16* pB1 = Bt + (size_t)(n0 + rA1) * 1024 + kc;
  // per-tile pointer deltas: MODE0 always +32; MODE1 alternates
  constexpr ptrdiff_t dEven = 32;  // dh: kc -> kc+32 (same head row)
  constexpr ptrdiff_t dOdd = (MODE == 0) ? 32 : (ptrdiff_t)S_ * DH_ - 32;

  bf16* dstA0 = smA0 + c0 * 512; bf16* dstA0b = smA0 + c1 * 512;
  bf16* dstA1 = smA1 + c0 * 512; bf16* dstA1b = smA1 + c1 * 512;
  bf16* dstB0 = smB0 + c0 * 512; bf16* dstB0b = smB0 + c1 * 512;
  bf16* dstB1 = smB1 + c0 * 512; bf16* dstB1b = smB1 + c1 * 512;

  // prologue: tile 0 (even) -> buf0, advance by even delta
  g2lds16(pA0, dstA0); g2lds16(pA1, dstA0b);
  g2lds16(pB0, dstB0); g2lds16(pB1, dstB0b);
  pA0 += dEven; pA1 += dEven; pB0 += dEven; pB1 += dEven;

  const int roA = (wm + r) * 32 + (quad ^ rx) * 8;
  const int roB = (wn + r) * 32 + (quad ^ rx) * 8;

  auto compute = [&](const bf16* bufA, const bf16* bufB) {
    bf16x8 af[4], bfr[4];
#pragma unroll
    for (int i = 0; i < 4; ++i) af[i] = *(const bf16x8*)(bufA + roA + i * 512);
#pragma unroll
    for (int j = 0; j < 4; ++j) bfr[j] = *(const bf16x8*)(bufB + roB + j * 512);
    if (which == 2) {
#pragma unroll
      for (int i = 0; i < 4; ++i)
#pragma unroll
        for (int j = 0; j < 4; ++j)
          acc[i][j] = __builtin_amdgcn_mfma_f32_16x16x32_bf16(bfr[i], af[j],
                                                              acc[i][j], 0, 0, 0);
    } else {
#pragma unroll
      for (int i = 0; i < 4; ++i)
#pragma unroll
        for (int j = 0; j < 4; ++j)
          acc[i][j] = __builtin_amdgcn_mfma_f32_16x16x32_bf16(af[i], bfr[j],
                                                              acc[i][j], 0, 0, 0);
    }
  };

#pragma unroll 1
  for (int kt = 0; kt < 32; kt += 2) {
    // half A: stage odd tile kt+1 -> buf1, compute buf0 (tile kt)
    g2lds16(pA0, dstA1); g2lds16(pA1, dstA1b);
    g2lds16(pB0, dstB1); g2lds16(pB1, dstB1b);
    pA0 += dOdd; pA1 += dOdd; pB0 += dEven; pB1 += dEven;
    asm volatile("s_waitcnt vmcnt(4)\n\ts_barrier" ::: "memory");
    compute(smA0, smB0);
    asm volatile("s_waitcnt lgkmcnt(0)\n\ts_barrier" ::: "memory");
    // half B: stage even tile kt+2 -> buf0, compute buf1 (tile kt+1)
    if (kt + 2 < 32) {
      g2lds16(pA0, dstA0); g2lds16(pA1, dstA0b);
      g2lds16(pB0, dstB0); g2lds16(pB1, dstB0b);
      pA0 += dEven; pA1 += dEven; pB0 += dEven; pB1 += dEven;
      asm volatile("s_waitcnt vmcnt(4)\n\ts_barrier" ::: "memory");
    } else {
      asm volatile("s_waitcnt vmcnt(0)\n\ts_barrier" ::: "memory");
    }
    compute(smA1, smB1);
    asm volatile("s_waitcnt lgkmcnt(0)\n\ts_barrier" ::: "memory");
  }

  if (which == 2) {  // acc[i][j]: row=n (dh), col=m (s)
#pragma unroll
    for (int i = 0; i < 4; ++i) {
#pragma unroll
      for (int j = 0; j < 4; ++j) {
#pragma unroll
        for (int g = 0; g < 4; ++g) {
          int n = n0 + wn + i * 16 + quad * 4 + g;
          int m = m0 + wm + j * 16 + r;
          Vto[((size_t)((m >> 11) * H_ + (n >> 6)) * DH_ + (n & 63)) * S_ +
              (m & 2047)] = (bf16)acc[i][j][g];
        }
      }
    }
    return;
  }
#pragma unroll
  for (int i = 0; i < 4; ++i) {
#pragma unroll
    for (int j = 0; j < 4; ++j) {
#pragma unroll
      for (int g = 0; g < 4; ++g) {
        int m = m0 + wm + i * 16 + quad * 4 + g;
        int n = n0 + wn + j * 16 + r;
        float v = acc[i][j][g];
        if constexpr (MODE == 0) {
          int b = m >> 11, s = m & 2047, h = n >> 6, dh = n & 63;
          if (which == 0)
            Qo[((size_t)(b * H_ + h) * S_ + s) * DH_ + dh] = (bf16)v;
          else
            Ko[((size_t)(b * H_ + h) * S_ + s) * DH_ + dh] = (bf16)v;
        } else {
          size_t idx = (size_t)m * 1024 + n;
          out[idx] = v + xres[idx];
        }
      }
    }
  }
}

// ------ flash attention v5: 32q/wave, register P (no LDS transpose) ------
// grid = 512: bh = bx & 63 (XCD-local), p = bx >> 6 pairs 128-q tiles
// (p, 15-p): 34 kv-64 iters each. S^T C-layout == A-operand layout of
// 16x16x16 MFMA -> PV directly from registers. Static-max softmax.
__global__ __launch_bounds__(256) void attn_kernel(const bf16* __restrict__ Qb,
                                                   const bf16* __restrict__ Kb,
                                                   const bf16* __restrict__ Vtb,
                                                   bf16* __restrict__ ctx) {
  __shared__ __align__(16) bf16 smK[2][64 * 64];
  __shared__ __align__(16) bf16 smV[2][64 * 64];
  const int bh = blockIdx.x & 63, p = blockIdx.x >> 6;
  const bf16* Qh = Qb + (size_t)bh * S_ * DH_;
  const bf16* Kh = Kb + (size_t)bh * S_ * DH_;
  const bf16* Vh = Vtb + (size_t)bh * DH_ * S_;
  bf16* Ch = ctx + (size_t)bh * S_ * DH_;
  const int tid = threadIdx.x, wave = tid >> 6, lane = tid & 63;
  const int quad = lane >> 4, r = lane & 15;
  const int r7 = r & 7;
  const int c0 = 2 * wave, c1 = c0 + 1;
  const int sr = lane >> 3;
  const int gcol = ((lane & 7) ^ (sr & 7)) * 8;  // source-side XOR swizzle
  const f32x4 zero = {0.f, 0.f, 0.f, 0.f};
  const int xk0 = (quad ^ r7) * 8, xk1 = ((quad + 4) ^ r7) * 8;

  for (int ph = 0; ph < 2; ++ph) {
    const int i128 = ph ? (15 - p) : p;
    const int qB = i128 * 128;
    const int q0w = qB + wave * 32;
    const int numkt = 2 * i128 + 2;

    bf16x8 qf[2][2];
    const float qsc = 0.125f * 1.44269504f;  // 1/sqrt(64) * log2(e)
#pragma unroll
    for (int qg = 0; qg < 2; ++qg)
#pragma unroll
      for (int hh = 0; hh < 2; ++hh) {
        bf16x8 q = *(const bf16x8*)(Qh + (size_t)(q0w + qg * 16 + r) * DH_ +
                                    hh * 32 + quad * 8);
#pragma unroll
        for (int i = 0; i < 8; ++i) q[i] = (bf16)((float)q[i] * qsc);
        qf[qg][hh] = q;
      }

    f32x4 lacc[2] = {zero, zero};
    f32x4 oacc[2][4];
#pragma unroll
    for (int qg = 0; qg < 2; ++qg)
#pragma unroll
      for (int tn = 0; tn < 4; ++tn) oacc[qg][tn] = zero;

    // prologue: tile 0 -> buffer 0
    g2lds16(Kh + (size_t)(c0 * 8 + sr) * DH_ + gcol, &smK[0][c0 * 512]);
    g2lds16(Kh + (size_t)(c1 * 8 + sr) * DH_ + gcol, &smK[0][c1 * 512]);
    g2lds16(Vh + (size_t)(c0 * 8 + sr) * S_ + gcol, &smV[0][c0 * 512]);
    g2lds16(Vh + (size_t)(c1 * 8 + sr) * S_ + gcol, &smV[0][c1 * 512]);

    for (int kt = 0; kt < numkt; ++kt) {
      const int cur = kt & 1;
      const int kv0 = kt * 64;
      if (kt + 1 < numkt) {  // prefetch next tile into other buffer
        const int nk = kv0 + 64;
        g2lds16(Kh + (size_t)(nk + c0 * 8 + sr) * DH_ + gcol, &smK[1 - cur][c0 * 512]);
        g2lds16(Kh + (size_t)(nk + c1 * 8 + sr) * DH_ + gcol, &smK[1 - cur][c1 * 512]);
        g2lds16(Vh + (size_t)(c0 * 8 + sr) * S_ + nk + gcol, &smV[1 - cur][c0 * 512]);
        g2lds16(Vh + (size_t)(c1 * 8 + sr) * S_ + nk + gcol, &smV[1 - cur][c1 * 512]);
        asm volatile("s_waitcnt vmcnt(4)\n\ts_barrier" ::: "memory");
      } else {
        asm volatile("s_waitcnt vmcnt(0)\n\ts_barrier" ::: "memory");
      }
      if (kv0 <= q0w + 31) {  // wave not fully masked for this kv tile
        const bf16* kb = &smK[cur][0];
        const bf16* vb = &smV[cur][0];

        // S^T: s[qg][t][g] = S[kv=kv0+t*16+quad*4+g][q=q0w+qg*16+r]
        f32x4 s[2][4];
#pragma unroll
        for (int t = 0; t < 4; ++t) {
          bf16x8 kf0 = *(const bf16x8*)(kb + (t * 16 + r) * 64 + xk0);
          bf16x8 kf1 = *(const bf16x8*)(kb + (t * 16 + r) * 64 + xk1);
#pragma unroll
          for (int qg = 0; qg < 2; ++qg) {
            f32x4 z = __builtin_amdgcn_mfma_f32_16x16x32_bf16(kf0, qf[qg][0],
                                                              zero, 0, 0, 0);
            s[qg][t] = __builtin_amdgcn_mfma_f32_16x16x32_bf16(kf1, qf[qg][1],
                                                               z, 0, 0, 0);
          }
        }
        if (kt >= numkt - 2) {  // diagonal region: causal mask
#pragma unroll
          for (int qg = 0; qg < 2; ++qg) {
            const int q = q0w + qg * 16 + r;
#pragma unroll
            for (int t = 0; t < 4; ++t) {
              const int kv = kv0 + t * 16 + quad * 4;
#pragma unroll
              for (int g = 0; g < 4; ++g)
                if (kv + g > q) s[qg][t][g] = -1e30f;
            }
          }
        }
        // P = exp2(s); l accumulate; PV via 16x16x16 MFMA (P from registers)
#pragma unroll
        for (int t = 0; t < 4; ++t) {
          bf16x4 pa[2];
#pragma unroll
          for (int qg = 0; qg < 2; ++qg) {
#pragma unroll
            for (int g = 0; g < 4; ++g)
              s[qg][t][g] = __builtin_amdgcn_exp2f(s[qg][t][g]);
            lacc[qg] += s[qg][t];
            bf16x4 pk;
#pragma unroll
            for (int g = 0; g < 4; ++g) pk[g] = (bf16)s[qg][t][g];
            pa[qg] = pk;
          }
#pragma unroll
          for (int tn = 0; tn < 4; ++tn) {
            bf16x4 vf = *(const bf16x4*)(
                vb + (tn * 16 + r) * 64 +
                ((2 * t + (quad >> 1)) ^ r7) * 8 + (quad & 1) * 4);
            oacc[0][tn] = mfma16(pa[0], vf, oacc[0][tn]);
            oacc[1][tn] = mfma16(pa[1], vf, oacc[1][tn]);
          }
        }
      }
      // all waves done reading cur buffers before next iter overwrites them
      asm volatile("s_waitcnt lgkmcnt(0)\n\ts_barrier" ::: "memory");
    }

    // epilogue: reduce l per q (= lane r) per qg, normalize, store
#pragma unroll
    for (int qg = 0; qg < 2; ++qg) {
      float rs = (lacc[qg][0] + lacc[qg][1]) + (lacc[qg][2] + lacc[qg][3]);
      rs += __shfl_xor(rs, 16, 64);
      rs += __shfl_xor(rs, 32, 64);
      const float inv = 1.f / rs;
      f32x4 ib;
#pragma unroll
      for (int g = 0; g < 4; ++g) ib[g] = __shfl(inv, quad * 4 + g, 64);
#pragma unroll
      for (int tn = 0; tn < 4; ++tn) {
        f32x4 ov = oacc[qg][tn] * ib;
#pragma unroll
        for (int g = 0; g < 4; ++g)
          Ch[(size_t)(q0w + qg * 16 + quad * 4 + g) * DH_ + tn * 16 + r] =
              (bf16)ov[g];
      }
    }
  }
}

// ---------------- LayerNorm in-place on d_out ----------------
__global__ __launch_bounds__(256) void ln_kernel(float* __restrict__ out,
                                                 const float* __restrict__ gamma,
                                                 const float* __restrict__ beta) {
  __shared__ float red[8];
  size_t row = blockIdx.x;
  float* p = out + row * 1024;
  int tid = threadIdx.x;
  float4 v = ((const float4*)p)[tid];
  float s1 = v.x + v.y + v.z + v.w;
  float s2 = v.x * v.x + v.y * v.y + v.z * v.z + v.w * v.w;
#pragma unroll
  for (int o = 1; o < 64; o <<= 1) {
    s1 += __shfl_xor(s1, o, 64);
    s2 += __shfl_xor(s2, o, 64);
  }
  int wave = tid >> 6, lane = tid & 63;
  if (lane == 0) { red[wave] = s1; red[4 + wave] = s2; }
  __syncthreads();
  s1 = red[0] + red[1] + red[2] + red[3];
  s2 = red[4] + red[5] + red[6] + red[7];
  float mean = s1 * (1.f / 1024.f);
  float var = s2 * (1.f / 1024.f) - mean * mean;
  float rstd = rsqrtf(var + 1e-5f);
  float4 g = ((const float4*)gamma)[tid];
  float4 b = ((const float4*)beta)[tid];
  float4 o;
  o.x = (v.x - mean) * rstd * g.x + b.x;
  o.y = (v.y - mean) * rstd * g.y + b.y;
  o.z = (v.z - mean) * rstd * g.z + b.z;
  o.w = (v.w - mean) * rstd * g.w + b.w;
  ((float4*)p)[tid] = o;
}

extern "C" void kernel_launch(void* const* d_in, const int* in_sizes, int n_in,
                              void* d_out, int out_size, void* d_ws,
                              size_t ws_size, hipStream_t stream) {
  (void)in_sizes; (void)n_in; (void)out_size; (void)ws_size;
  const float* x  = (const float*)d_in[0];
  const float* WQ = (const float*)d_in[1];
  const float* WK = (const float*)d_in[2];
  const float* WV = (const float*)d_in[3];
  const float* WO = (const float*)d_in[4];
  const float* gamma = (const float*)d_in[5];
  const float* beta  = (const float*)d_in[6];
  float* out = (float*)d_out;

  bf16* ws = (bf16*)d_ws;
  const size_t MD = (size_t)M_ * D_;
  const size_t WW = (size_t)D_ * D_;
  bf16* xb   = ws;
  bf16* wqt  = xb + MD;
  bf16* wkt  = wqt + WW;
  bf16* wvt  = wkt + WW;
  bf16* wot  = wvt + WW;
  bf16* Qb   = wot + WW;
  bf16* Kb   = Qb + MD;
  bf16* Vtb  = Kb + MD;
  bf16* ctxb = Vtb + MD;

  cvt_all_kernel<<<dim3(8192), dim3(256), 0, stream>>>(
      x, WQ, WK, WV, WO, xb, wqt, wkt, wvt, wot);
  gemm_kernel<0><<<dim3(64 * 24), dim3(256), 0, stream>>>(
      xb, wqt, wkt, wvt, Qb, Kb, Vtb, nullptr, nullptr);
  attn_kernel<<<dim3(512), dim3(256), 0, stream>>>(Qb, Kb, Vtb, ctxb);
  gemm_kernel<1><<<dim3(64 * 8), dim3(256), 0, stream>>>(
      ctxb, wot, nullptr, nullptr, nullptr, nullptr, nullptr, x, out);
  ln_kernel<<<dim3(8192), dim3(256), 0, stream>>>(out, gamma, beta);
}